// Round 2
// baseline (79.782 us; speedup 1.0000x reference)
//
#include <hip/hip_runtime.h>
#include <math.h>

// Problem constants (match reference)
#define B_      16
#define T_      2048
#define NFREQ_  1152
#define NOCT_   9
#define EPS_    1e-4f
#define NCH_    32           // t-chunks per batch (grid y) -> 512 blocks, 2/CU
#define CT_     (T_ / NCH_)  // 64 t per block
#define QT_     (CT_ / 4)    // 16 t per quarter (block = 4 quarters x 128 lanes)
#define CSTRIDE 19           // comb LDS stride (18 payload + 1 pad; gcd(19,32)=1)

// Kernel 1: for each (b, t-chunk), lane = base frequency (128 of them),
// 9 octaves derived per lane by exact angle doubling (1 sincos per t per lane).
// Each block writes its partial sums to a PRIVATE slot: no atomics, no memset.
__global__ __launch_bounds__(512) void spectral_main(
    const float* __restrict__ batch, const float* __restrict__ freqs,
    float* __restrict__ part)
{
  const int b      = blockIdx.x;
  const int ch     = blockIdx.y;
  const int tid    = threadIdx.x;
  const int lane_f = tid & 127;
  const int q      = tid >> 7;
  const int t0     = ch * CT_;

  const float* ts = batch + (size_t)b * 2 * T_;
  const float* ys = ts + T_;

  __shared__ float lds_ts[CT_], lds_y[CT_];
  __shared__ float wsum[8], wsq[8];
  __shared__ float comb[4 * 128 * CSTRIDE];

  // stage this block's chunk (threads 0..2*CT_-1)
  if (tid < CT_)           lds_ts[tid]      = ts[t0 + tid];
  else if (tid < 2 * CT_)  lds_y[tid - CT_] = ys[t0 + tid - CT_];

  // --- per-batch stats of ys: one float4 per thread + shuffle reduce ---
  float4 v = ((const float4*)ys)[tid];           // 512 threads x 16B = 2048 f32
  float lsum = v.x + v.y + v.z + v.w;
  float lsq  = fmaf(v.x, v.x, fmaf(v.y, v.y, fmaf(v.z, v.z, v.w * v.w)));
#pragma unroll
  for (int off = 32; off > 0; off >>= 1) {
    lsum += __shfl_xor(lsum, off, 64);
    lsq  += __shfl_xor(lsq,  off, 64);
  }
  const int w = tid >> 6;
  if ((tid & 63) == 0) { wsum[w] = lsum; wsq[w] = lsq; }
  __syncthreads();
  float s1 = 0.f, s2 = 0.f;
#pragma unroll
  for (int k = 0; k < 8; ++k) { s1 += wsum[k]; s2 += wsq[k]; }
  const float mean  = s1 * (1.f / T_);
  const float var   = (s2 - (float)T_ * mean * mean) * (1.f / (T_ - 1));
  const float inv_s = 1.f / (sqrtf(fmaxf(var, 0.f)) + EPS_);
  if (tid < CT_) lds_y[tid] = (lds_y[tid] - mean) * inv_s;
  __syncthreads();

  // --- main loop: 1 sincos per t, octave doubling for the other 8 ---
  const float fr = freqs[lane_f];  // base-octave frequency (cycles per unit)
  float p1[NOCT_], p2[NOCT_];
#pragma unroll
  for (int o = 0; o < NOCT_; ++o) { p1[o] = 0.f; p2[o] = 0.f; }

  const int tb = q * QT_;
#pragma unroll 2
  for (int i = 0; i < QT_; ++i) {
    float z = lds_ts[tb + i];   // wave-uniform broadcast (conflict-free)
    float y = lds_y[tb + i];
    float rev = z * fr;                         // revolutions = ts * f
    float rf  = rev - floorf(rev);              // range-reduce to [0,1)
    float s = __builtin_amdgcn_sinf(rf);        // v_sin_f32: sin(2*pi*x)
    float c = __builtin_amdgcn_cosf(rf);
#pragma unroll
    for (int o = 0; o < NOCT_; ++o) {
      p1[o] = fmaf(y, s, p1[o]);
      p2[o] = fmaf(y, c, p2[o]);
      if (o < NOCT_ - 1) {
        float sc = s * c;
        c = fmaf(2.f * c, c, -1.f);             // cos(2x) = 2c^2 - 1 (exact id.)
        s = sc + sc;                            // sin(2x) = 2sc
      }
    }
  }

  // --- combine 4 quarters via LDS, write private partial slot (coalesced) ---
  const int cb = (q * 128 + lane_f) * CSTRIDE;
#pragma unroll
  for (int o = 0; o < NOCT_; ++o) {
    comb[cb + o]     = p1[o];
    comb[cb + 9 + o] = p2[o];
  }
  __syncthreads();
  float* pb = part + ((size_t)b * NCH_ + ch) * (2 * NFREQ_);
  for (int m = tid; m < 2 * NFREQ_; m += 512) {
    int p = m >= NFREQ_;
    int r = m - p * NFREQ_;
    int o = r >> 7, lf = r & 127;
    int slot = p * 9 + o;
    float acc = comb[(0 * 128 + lf) * CSTRIDE + slot]
              + comb[(1 * 128 + lf) * CSTRIDE + slot]
              + comb[(2 * 128 + lf) * CSTRIDE + slot]
              + comb[(3 * 128 + lf) * CSTRIDE + slot];
    pb[m] = acc;
  }
}

// Kernel 2: sum the 32 chunk-partials, mag = sqrt(p1^2+p2^2),
// tnorm over the 1152 freqs (ddof=1), write output.
__global__ __launch_bounds__(256) void spectral_final(
    const float* __restrict__ part, float* __restrict__ out)
{
  const int b   = blockIdx.x;
  const int tid = threadIdx.x;
  __shared__ float mag[NFREQ_];
  __shared__ float w1[4], w2[4];
  const float* pb = part + (size_t)b * NCH_ * (2 * NFREQ_);

  float lsum = 0.f, lsq = 0.f;
  for (int f = tid; f < NFREQ_; f += 256) {
    float a = 0.f, c = 0.f;
#pragma unroll 8
    for (int ch = 0; ch < NCH_; ++ch) {
      a += pb[(size_t)ch * (2 * NFREQ_) + f];
      c += pb[(size_t)ch * (2 * NFREQ_) + NFREQ_ + f];
    }
    float m = sqrtf(fmaf(a, a, c * c));
    mag[f] = m;
    lsum += m; lsq = fmaf(m, m, lsq);
  }
#pragma unroll
  for (int off = 32; off > 0; off >>= 1) {
    lsum += __shfl_xor(lsum, off, 64);
    lsq  += __shfl_xor(lsq,  off, 64);
  }
  const int w = tid >> 6;
  if ((tid & 63) == 0) { w1[w] = lsum; w2[w] = lsq; }
  __syncthreads();
  float s1 = w1[0] + w1[1] + w1[2] + w1[3];
  float s2 = w2[0] + w2[1] + w2[2] + w2[3];
  float mean = s1 * (1.f / NFREQ_);
  float var  = (s2 - (float)NFREQ_ * mean * mean) * (1.f / (NFREQ_ - 1));
  float inv  = 1.f / (sqrtf(fmaxf(var, 0.f)) + EPS_);
  for (int f = tid; f < NFREQ_; f += 256)
    out[(size_t)b * NFREQ_ + f] = (mag[f] - mean) * inv;
}

extern "C" void kernel_launch(void* const* d_in, const int* in_sizes, int n_in,
                              void* d_out, int out_size, void* d_ws, size_t ws_size,
                              hipStream_t stream) {
  const float* batch = (const float*)d_in[0];   // (16, 2, 2048) f32
  const float* freqs = (const float*)d_in[1];   // (1152,) f32
  float* out  = (float*)d_out;                  // (16, 1, 1152) f32
  float* part = (float*)d_ws;                   // [16][32][2304] f32 = 4.7 MB

  spectral_main<<<dim3(B_, NCH_), 512, 0, stream>>>(batch, freqs, part);
  spectral_final<<<B_, 256, 0, stream>>>(part, out);
}